// Round 1
// 1082.744 us; speedup vs baseline: 1.0843x; 1.0843x over previous
//
#include <hip/hip_runtime.h>
#include <math.h>

#define N_ATOMS 50000
#define P_PAIRS 1600000
#define TA 16
#define CAP_MAX 96

__device__ __forceinline__ float gelu_exact(float x) {
    return 0.5f * x * (1.0f + erff(x * 0.70710678118654752440f));
}

// Invert pair->atom index: bucket[idx][pos] = pair id.
__global__ __launch_bounds__(256) void build_buckets(
    const int* __restrict__ idx_j,
    int* __restrict__ cnt,
    int* __restrict__ bucket,
    int cap)
{
    int p = blockIdx.x * 256 + threadIdx.x;
    int idx = idx_j[p];
    int pos = atomicAdd(cnt + idx, 1);
    if (pos < cap) bucket[(size_t)idx * cap + pos] = p;
}

__global__ __launch_bounds__(256, 3) void fused_atom_kernel(
    const float* __restrict__ emb,
    const float* __restrict__ qch,
    const int* __restrict__ cnt,
    const int* __restrict__ bucket,
    const float* __restrict__ gs,
    const float* __restrict__ gv,
    const float* __restrict__ agh,   // (128,16,32) -> [a*512 + g*32 + h]
    const float* __restrict__ W_gf,  // (16,128)
    const float* __restrict__ W1, const float* __restrict__ b1,   // (320,256)
    const float* __restrict__ W2, const float* __restrict__ b2,   // (256,128)
    const float* __restrict__ W3, const float* __restrict__ b3,   // (128,130)
    int cap,
    float* __restrict__ out)
{
    // bufA: embT [128][16]            then h1T [256][16]
    // bufB: U    [16][512]  then msgT [320][16]  then h2T [128][16]
    __shared__ __align__(16) float s_bufA[16 * 256];   // 16 KB
    __shared__ __align__(16) float s_bufB[16 * 512];   // 32 KB
    __shared__ __align__(16) float s_gs[16 * 16];      // [atom][g]
    __shared__ __align__(16) float s_gv[16 * 48];      // [atom][d*16+g]
    __shared__ __align__(16) float s_q[16];

    const int tid = threadIdx.x;
    const int n0 = blockIdx.x * TA;

    float* s_embT = s_bufA;   // [a][atom]
    float* s_h1T  = s_bufA;   // [k][atom]
    float* s_U    = s_bufB;   // [atom][gh]
    float* s_msgT = s_bufB;   // [k][atom]  (aliases U after it's consumed)
    float* s_h2T  = s_bufB;   // [k][atom]

    // ---- stage emb (transposed into LDS) ----
    #pragma unroll
    for (int i = 0; i < 2; i++) {
        int ii = tid + i * 256;           // float4 index, 512 total
        int atom = ii >> 5;               // 32 float4 per atom row
        int a4 = (ii & 31) * 4;
        float4 v = *(const float4*)(emb + (size_t)(n0 + atom) * 128 + a4);
        s_embT[(a4 + 0) * 16 + atom] = v.x;
        s_embT[(a4 + 1) * 16 + atom] = v.y;
        s_embT[(a4 + 2) * 16 + atom] = v.z;
        s_embT[(a4 + 3) * 16 + atom] = v.w;
    }

    // ---- gather per-atom gs/gv sums from pair buckets ----
    {
        const int g = tid >> 4;           // atom within tile
        const int l = tid & 15;           // 16 lanes cover 64 components
        const int n = n0 + g;
        int c = cnt[n]; if (c > cap) c = cap;
        const int* brow = bucket + (size_t)n * cap;
        const float* base; int stride;
        if (l < 4) { base = gs + l * 4;       stride = 16; }
        else       { base = gv + (l - 4) * 4; stride = 48; }
        float4 a = make_float4(0.f, 0.f, 0.f, 0.f);
        int i = 0;
        for (; i + 4 <= c; i += 4) {
            int p0 = brow[i + 0], p1 = brow[i + 1];
            int p2 = brow[i + 2], p3 = brow[i + 3];
            float4 v0 = *(const float4*)(base + (size_t)p0 * stride);
            float4 v1 = *(const float4*)(base + (size_t)p1 * stride);
            float4 v2 = *(const float4*)(base + (size_t)p2 * stride);
            float4 v3 = *(const float4*)(base + (size_t)p3 * stride);
            a.x += (v0.x + v1.x) + (v2.x + v3.x);
            a.y += (v0.y + v1.y) + (v2.y + v3.y);
            a.z += (v0.z + v1.z) + (v2.z + v3.z);
            a.w += (v0.w + v1.w) + (v2.w + v3.w);
        }
        for (; i < c; i++) {
            int p0 = brow[i];
            float4 v0 = *(const float4*)(base + (size_t)p0 * stride);
            a.x += v0.x; a.y += v0.y; a.z += v0.z; a.w += v0.w;
        }
        if (l < 4) *(float4*)(s_gs + g * 16 + l * 4)       = a;
        else       *(float4*)(s_gv + g * 48 + (l - 4) * 4) = a;
    }
    if (tid < 16) s_q[tid] = qch[n0 + tid];
    __syncthreads();

    // ---- U[atom][gh] = sum_a emb[atom][a] * agh[a][gh] ----
    {
        const int gh4  = (tid & 127) * 4;   // 4 consecutive gh
        const int half = tid >> 7;          // atoms half*8 .. +7
        float u[32];
        #pragma unroll
        for (int i = 0; i < 32; i++) u[i] = 0.f;
        #pragma unroll 4
        for (int a = 0; a < 128; a++) {
            float4 w  = *(const float4*)(agh + a * 512 + gh4);
            float4 e0 = *(const float4*)(s_embT + a * 16 + half * 8);
            float4 e1 = *(const float4*)(s_embT + a * 16 + half * 8 + 4);
            float wv[4] = {w.x, w.y, w.z, w.w};
            float ev[8] = {e0.x, e0.y, e0.z, e0.w, e1.x, e1.y, e1.z, e1.w};
            #pragma unroll
            for (int j = 0; j < 4; j++)
                #pragma unroll
                for (int m = 0; m < 8; m++)
                    u[j * 8 + m] += wv[j] * ev[m];
        }
        #pragma unroll
        for (int m = 0; m < 8; m++) {
            int atom = half * 8 + m;
            float4 v = {u[0 * 8 + m], u[1 * 8 + m], u[2 * 8 + m], u[3 * 8 + m]};
            *(float4*)(s_U + atom * 512 + gh4) = v;
        }
    }
    __syncthreads();

    // ---- avf + safe_norm -> registers (U is consumed here) ----
    float nrm[2];
    #pragma unroll
    for (int it = 0; it < 2; it++) {
        int i = tid + it * 256;
        int atom = i >> 5, h = i & 31;
        float v0 = 0.f, v1 = 0.f, v2 = 0.f;
        #pragma unroll
        for (int g = 0; g < 16; g++) {
            float uv = s_U[atom * 512 + g * 32 + h];
            v0 += uv * s_gv[atom * 48 + g];
            v1 += uv * s_gv[atom * 48 + 16 + g];
            v2 += uv * s_gv[atom * 48 + 32 + g];
        }
        float sq = v0 * v0 + v1 * v1 + v2 * v2;
        nrm[it] = (sq > 0.f) ? sqrtf(sq) : 0.f;
    }
    __syncthreads();   // all U reads done; bufB is now msgT

    // ---- write vec_emb rows [128,160) ; zero rows [288,320) ----
    #pragma unroll
    for (int it = 0; it < 2; it++) {
        int i = tid + it * 256;
        int atom = i >> 5, h = i & 31;
        s_msgT[(128 + h) * 16 + atom] = nrm[it];
        s_msgT[(288 + h) * 16 + atom] = 0.f;
    }

    // ---- mapped = GS_sum @ W_gf ; rad_emb rows [0,128) ; rad_q rows [160,288) ----
    {
        const int f = tid & 127;
        const int half = tid >> 7;
        float mp[8];
        #pragma unroll
        for (int a = 0; a < 8; a++) mp[a] = 0.f;
        #pragma unroll
        for (int g = 0; g < 16; g++) {
            float w = W_gf[g * 128 + f];
            #pragma unroll
            for (int a = 0; a < 8; a++)
                mp[a] += s_gs[(half * 8 + a) * 16 + g] * w;
        }
        #pragma unroll
        for (int a = 0; a < 8; a++) {
            int atom = half * 8 + a;
            float e = s_embT[f * 16 + atom];
            s_msgT[f * 16 + atom]         = e * mp[a];
            s_msgT[(160 + f) * 16 + atom] = s_q[atom] * mp[a];
        }
    }
    __syncthreads();

    // ---- MLP layer 1: h1 = gelu(msg @ W1 + b1), 320 -> 256 ----
    {
        const int o4 = (tid & 63) * 4;      // 4 consecutive output cols
        const int q4 = (tid >> 6) * 4;      // 4 consecutive atoms
        float acc1[16];
        #pragma unroll
        for (int i = 0; i < 16; i++) acc1[i] = 0.f;
        #pragma unroll 4
        for (int k = 0; k < 320; k++) {
            float4 w  = *(const float4*)(W1 + k * 256 + o4);
            float4 mm = *(const float4*)(s_msgT + k * 16 + q4);
            float wv[4] = {w.x, w.y, w.z, w.w};
            float mv[4] = {mm.x, mm.y, mm.z, mm.w};
            #pragma unroll
            for (int j = 0; j < 4; j++)
                #pragma unroll
                for (int m = 0; m < 4; m++)
                    acc1[j * 4 + m] += wv[j] * mv[m];
        }
        #pragma unroll
        for (int j = 0; j < 4; j++) {
            int o = o4 + j;
            float bb = b1[o];
            float4 v;
            v.x = gelu_exact(acc1[j * 4 + 0] + bb);
            v.y = gelu_exact(acc1[j * 4 + 1] + bb);
            v.z = gelu_exact(acc1[j * 4 + 2] + bb);
            v.w = gelu_exact(acc1[j * 4 + 3] + bb);
            *(float4*)(s_h1T + o * 16 + q4) = v;
        }
    }
    __syncthreads();

    // ---- MLP layer 2: h2 = gelu(h1 @ W2 + b2), 256 -> 128 ----
    {
        const int o4 = (tid & 31) * 4;
        const int a2 = (tid >> 5) * 2;
        float acc2[8];
        #pragma unroll
        for (int i = 0; i < 8; i++) acc2[i] = 0.f;
        #pragma unroll 4
        for (int k = 0; k < 256; k++) {
            float4 w  = *(const float4*)(W2 + k * 128 + o4);
            float2 hh = *(const float2*)(s_h1T + k * 16 + a2);
            float wv[4] = {w.x, w.y, w.z, w.w};
            float hv[2] = {hh.x, hh.y};
            #pragma unroll
            for (int j = 0; j < 4; j++)
                #pragma unroll
                for (int m = 0; m < 2; m++)
                    acc2[j * 2 + m] += wv[j] * hv[m];
        }
        __syncthreads();   // h1T reads done before h2T overwrites bufB region
        #pragma unroll
        for (int j = 0; j < 4; j++) {
            int o = o4 + j;
            float bb = b2[o];
            float2 v;
            v.x = gelu_exact(acc2[j * 2 + 0] + bb);
            v.y = gelu_exact(acc2[j * 2 + 1] + bb);
            *(float2*)(s_h2T + o * 16 + a2) = v;
        }
    }
    __syncthreads();

    // ---- MLP layer 3: out = h2 @ W3 + b3, 128 -> 130 ----
    {
        const int o4 = (tid & 31) * 4 + 2;   // cols 2..129 (delta_a)
        const int a2 = (tid >> 5) * 2;
        float acc3[8];
        #pragma unroll
        for (int i = 0; i < 8; i++) acc3[i] = 0.f;
        #pragma unroll 4
        for (int k = 0; k < 128; k++) {
            const float* wp = W3 + k * 130 + o4;     // even element offset -> 8B aligned
            float2 wa = *(const float2*)(wp);
            float2 wb = *(const float2*)(wp + 2);
            float2 hh = *(const float2*)(s_h2T + k * 16 + a2);
            float wv[4] = {wa.x, wa.y, wb.x, wb.y};
            float hv[2] = {hh.x, hh.y};
            #pragma unroll
            for (int j = 0; j < 4; j++)
                #pragma unroll
                for (int m = 0; m < 2; m++)
                    acc3[j * 2 + m] += wv[j] * hv[m];
        }
        #pragma unroll
        for (int m = 0; m < 2; m++) {
            int n = n0 + a2 + m;
            float4 v;
            v.x = acc3[0 * 2 + m] + b3[o4 + 0];
            v.y = acc3[1 * 2 + m] + b3[o4 + 1];
            v.z = acc3[2 * 2 + m] + b3[o4 + 2];
            v.w = acc3[3 * 2 + m] + b3[o4 + 3];
            *(float4*)(out + (size_t)n * 128 + (o4 - 2)) = v;
        }

        // delta_q (col 0) and f (col 1)
        if (tid < 32) {
            int atom = tid >> 1, col = tid & 1;
            float s = 0.f;
            #pragma unroll 4
            for (int k = 0; k < 128; k++)
                s += s_h2T[k * 16 + atom] * W3[k * 130 + col];
            s += b3[col];
            out[(size_t)N_ATOMS * 128 + (size_t)col * N_ATOMS + (n0 + atom)] = s;
        }
    }
}

extern "C" void kernel_launch(void* const* d_in, const int* in_sizes, int n_in,
                              void* d_out, int out_size, void* d_ws, size_t ws_size,
                              hipStream_t stream)
{
    const float* emb  = (const float*)d_in[0];
    const float* qch  = (const float*)d_in[1];
    const int*   pidx = (const int*)d_in[2];
    const float* gs   = (const float*)d_in[3];
    const float* gv   = (const float*)d_in[4];
    const float* agh  = (const float*)d_in[5];
    const float* W_gf = (const float*)d_in[6];
    const float* W1   = (const float*)d_in[7];
    const float* b1   = (const float*)d_in[8];
    const float* W2   = (const float*)d_in[9];
    const float* b2   = (const float*)d_in[10];
    const float* W3   = (const float*)d_in[11];
    const float* b3   = (const float*)d_in[12];

    // workspace: cnt (N int) | bucket (N * cap int)
    int* cnt = (int*)d_ws;
    const size_t cnt_off = 256 * 1024;
    int* bucket = (int*)((char*)d_ws + cnt_off);
    size_t avail = (ws_size > cnt_off) ? (ws_size - cnt_off) : 0;
    size_t cap_fit = avail / ((size_t)N_ATOMS * sizeof(int));
    int cap = cap_fit > CAP_MAX ? CAP_MAX : (int)cap_fit;

    hipMemsetAsync(cnt, 0, (size_t)N_ATOMS * sizeof(int), stream);

    build_buckets<<<P_PAIRS / 256, 256, 0, stream>>>(
        pidx + P_PAIRS, cnt, bucket, cap);

    fused_atom_kernel<<<N_ATOMS / TA, 256, 0, stream>>>(
        emb, qch, cnt, bucket, gs, gv, agh, W_gf,
        W1, b1, W2, b2, W3, b3, cap, (float*)d_out);
}